// Round 3
// baseline (171.156 us; speedup 1.0000x reference)
//
#include <hip/hip_runtime.h>
#include <hip/hip_bf16.h>
#include <stdint.h>

// Problem constants (match reference)
#define B_SZ 8
#define T_LEN 1024
#define C_DIM 1024
#define M_ROWS (B_SZ * T_LEN)   // 8192
#define NCH 32
#define CHL (T_LEN / NCH)       // 32

typedef unsigned short ushort_t;
typedef __attribute__((ext_vector_type(8))) short short8;
typedef __attribute__((ext_vector_type(4))) float f32x4;
typedef __attribute__((ext_vector_type(4))) unsigned short us4;

static __device__ __forceinline__ float bf2f(ushort_t u) {
  union { unsigned int i; float f; } x; x.i = ((unsigned int)u) << 16; return x.f;
}
static __device__ __forceinline__ ushort_t f2bf(float f) {
  union { float f; unsigned int i; } x; x.f = f;
  unsigned int r = x.i + 0x7fffu + ((x.i >> 16) & 1u);
  return (ushort_t)(r >> 16);
}

static __device__ __forceinline__ void gload_lds16(const void* g, void* l) {
  __builtin_amdgcn_global_load_lds(
      (const __attribute__((address_space(1))) void*)g,
      (__attribute__((address_space(3))) void*)l, 16, 0, 0);
}

// ---------------- weight f32 -> bf16 conversion (vectorized x4) ------------
__global__ void cvt_w_kernel(const float* __restrict__ wk, const float* __restrict__ wv,
                             const float* __restrict__ wr, const float* __restrict__ wo,
                             ushort_t* __restrict__ out) {
  int gid = blockIdx.x * 256 + threadIdx.x;
  int which = gid >> 18;
  int off = (gid << 2) & ((1 << 20) - 1);
  const float* src = which == 0 ? wk : which == 1 ? wv : which == 2 ? wr : wo;
  float4 v = *(const float4*)(src + off);
  us4 o = {f2bf(v.x), f2bf(v.y), f2bf(v.z), f2bf(v.w)};
  *(us4*)(out + (size_t)gid * 4) = o;
}

// ---------------- time-shift mixing -> bf16 xm (vectorized x4) -------------
__global__ void xm_kernel(const float* __restrict__ x, const float* __restrict__ tm,
                          const float* __restrict__ cm, ushort_t* __restrict__ xmb) {
  int gid = blockIdx.x * 256 + threadIdx.x;
  int c4 = (gid & (C_DIM / 4 - 1)) * 4;
  int t = (gid >> 8) & (T_LEN - 1);
  const float4 zero = {0.f, 0.f, 0.f, 0.f};
  float4 xv = *(const float4*)(x + (size_t)gid * 4);
  float4 xp = (t > 0) ? *(const float4*)(x + (size_t)gid * 4 - C_DIM) : zero;
  float4 xn = (t < T_LEN - 1) ? *(const float4*)(x + (size_t)gid * 4 + C_DIM) : zero;
  float4 tmv = *(const float4*)(tm + c4);
  float4 cmv = *(const float4*)(cm + c4);
  float4 xc = (c4 < C_DIM / 2) ? xp : xn;
  us4 o;
  o.x = f2bf(xv.x * tmv.x + xp.x * (1.f - tmv.x) + xc.x * cmv.x);
  o.y = f2bf(xv.y * tmv.y + xp.y * (1.f - tmv.y) + xc.y * cmv.y);
  o.z = f2bf(xv.z * tmv.z + xp.z * (1.f - tmv.z) + xc.z * cmv.z);
  o.w = f2bf(xv.w * tmv.w + xp.w * (1.f - tmv.w) + xc.w * cmv.w);
  *(us4*)(xmb + (size_t)gid * 4) = o;
}

// ======================= 256x256 8-phase fused GEMM ========================
// C = A(8192x1024) * W^T for W in {Wk,Wv,Wr}; logical N=3072 split into 12
// column tiles of 256; mode = tile>>2 selects epilogue/output.
// Template: BM=BN=256, BK=64, 8 waves (2M x 4N interleaved), 128 KiB LDS,
// 8 phases per 2 K-tiles, counted vmcnt(6) at phases 4/8, setprio around MFMA.
// LDS swizzle: 16B-chunk index ^= (row&7); applied on global source col
// (linear gload_lds dest) and on ds_read address.

#define RDA(buf, mh)                                                          \
  {                                                                           \
    _Pragma("unroll") for (int mq = 0; mq < 4; ++mq) {                        \
      _Pragma("unroll") for (int ks = 0; ks < 2; ++ks) {                      \
        const int row = ((mh)*4 + mq) * 32 + wm * 16 + fr;                    \
        const int cp = ((ks * 4 + kq) ^ (fr & 7)) * 8;                        \
        a_fr[mq][ks] = *(const short8*)&lds[buf][0][row * 64 + cp];           \
      }                                                                       \
    }                                                                         \
  }

#define RDB(buf, nh)                                                          \
  {                                                                           \
    _Pragma("unroll") for (int nq = 0; nq < 2; ++nq) {                        \
      _Pragma("unroll") for (int ks = 0; ks < 2; ++ks) {                      \
        const int row = ((nh)*2 + nq) * 64 + wn * 16 + fr;                    \
        const int cp = ((ks * 4 + kq) ^ (fr & 7)) * 8;                        \
        b_fr[(nh)*2 + nq][ks] = *(const short8*)&lds[buf][1][row * 64 + cp];  \
      }                                                                       \
    }                                                                         \
  }

#define DOMFMA(mh, nh)                                                        \
  {                                                                           \
    _Pragma("unroll") for (int mq = 0; mq < 4; ++mq) {                        \
      _Pragma("unroll") for (int nq = 0; nq < 2; ++nq) {                      \
        _Pragma("unroll") for (int ks = 0; ks < 2; ++ks) {                    \
          acc[(mh)*4 + mq][(nh)*2 + nq] =                                     \
              __builtin_amdgcn_mfma_f32_16x16x32_bf16(                        \
                  a_fr[mq][ks], b_fr[(nh)*2 + nq][ks],                        \
                  acc[(mh)*4 + mq][(nh)*2 + nq], 0, 0, 0);                    \
        }                                                                     \
      }                                                                       \
    }                                                                         \
  }

#define VM6 asm volatile("s_waitcnt vmcnt(6)" ::: "memory");
#define VM0 asm volatile("s_waitcnt vmcnt(0)" ::: "memory");

#define MFMA_BLOCK(mh, nh, VMW)                                               \
  __builtin_amdgcn_s_barrier();                                               \
  asm volatile("s_waitcnt lgkmcnt(0)" ::: "memory");                          \
  __builtin_amdgcn_sched_barrier(0);                                          \
  __builtin_amdgcn_s_setprio(1);                                              \
  DOMFMA(mh, nh);                                                             \
  __builtin_amdgcn_s_setprio(0);                                              \
  VMW                                                                         \
  __builtin_amdgcn_s_barrier();                                               \
  __builtin_amdgcn_sched_barrier(0);

__global__ __launch_bounds__(512, 2) void gemm256(const ushort_t* __restrict__ A,
                                                  const ushort_t* __restrict__ Bw,
                                                  float* __restrict__ outK,
                                                  ushort_t* __restrict__ outV,
                                                  ushort_t* __restrict__ outR) {
  __shared__ ushort_t lds[2][2][16384];  // [buf][A/B][256 rows x 64 cols bf16]

  const int tid = threadIdx.x;
  const int lane = tid & 63;
  const int wid = tid >> 6;
  const int wm = wid >> 2;      // 0..1
  const int wn = wid & 3;       // 0..3
  const int fr = lane & 15;
  const int kq = lane >> 4;

  // XCD-aware swizzle (nwg=384, 384%8==0 -> simple form bijective)
  const int lid = blockIdx.x;
  const int swz = (lid & 7) * 48 + (lid >> 3);
  const int bm = (swz & 31) * 256;
  const int jb = swz >> 5;            // 0..11
  const int mode = jb >> 2;           // 0:k 1:v 2:r
  const int bn = (jb & 3) * 256;
  const ushort_t* Bp = Bw + ((size_t)mode << 20);

  f32x4 acc[8][4];
#pragma unroll
  for (int m = 0; m < 8; ++m)
#pragma unroll
    for (int n = 0; n < 4; ++n) acc[m][n] = (f32x4){0.f, 0.f, 0.f, 0.f};

  short8 a_fr[4][2];
  short8 b_fr[4][2];

  // staging addressing: thread t covers LDS bytes [t*16, t*16+16) of a
  // 64-row sub-panel; global col pre-swizzled: chunk = (t&7) ^ (row&7)
  const int srow = tid >> 3;                          // 0..63
  const int scol = ((tid & 7) ^ (srow & 7)) * 8;      // element col
  const ushort_t* Ag = A + (size_t)(bm + srow) * 1024 + scol;
  const ushort_t* Bg = Bp + (size_t)(bn + srow) * 1024 + scol;

  auto stage = [&](int buf, int kt, int s) {
    // s: 0=A.h0  1=B.h1  2=A.h1  3=B.h0
    const int op = (s == 1 || s == 3) ? 1 : 0;
    const int h = (s == 1 || s == 2) ? 1 : 0;
    const ushort_t* g = (op ? Bg : Ag) + (size_t)(h * 128) * 1024 + kt * 64;
    ushort_t* dst = &lds[buf][op][h * 8192 + tid * 8];
    gload_lds16(g, dst);
    gload_lds16(g + 64 * 1024, dst + 4096);
  };

  // prologue: kt0 fully + kt1 first 3 halves; vmcnt(6) leaves kt1.h1-3 in flight
  stage(0, 0, 0); stage(0, 0, 1); stage(0, 0, 2); stage(0, 0, 3);
  stage(1, 1, 0); stage(1, 1, 1); stage(1, 1, 2);
  VM6
  __builtin_amdgcn_s_barrier();

#pragma unroll 1
  for (int i = 0; i < 7; ++i) {
    const int kt = 2 * i;
    // ---- K-tile kt (buf0) ----
    RDA(0, 0) RDB(0, 0)
    stage(1, kt + 1, 3);
    MFMA_BLOCK(0, 0, )
    RDB(0, 1)
    stage(0, kt + 2, 0);
    MFMA_BLOCK(0, 1, )
    RDA(0, 1)
    stage(0, kt + 2, 1);
    MFMA_BLOCK(1, 1, )
    stage(0, kt + 2, 2);
    MFMA_BLOCK(1, 0, VM6)
    // ---- K-tile kt+1 (buf1) ----
    RDA(1, 0) RDB(1, 0)
    stage(0, kt + 2, 3);
    MFMA_BLOCK(0, 0, )
    RDB(1, 1)
    stage(1, kt + 3, 0);
    MFMA_BLOCK(0, 1, )
    RDA(1, 1)
    stage(1, kt + 3, 1);
    MFMA_BLOCK(1, 1, )
    stage(1, kt + 3, 2);
    MFMA_BLOCK(1, 0, VM6)
  }
  // ---- epilogue: kt=14 (buf0), kt=15 (buf1); only kt15.h4 left to stage ----
  RDA(0, 0) RDB(0, 0)
  stage(1, 15, 3);
  MFMA_BLOCK(0, 0, )
  RDB(0, 1)
  MFMA_BLOCK(0, 1, )
  RDA(0, 1)
  MFMA_BLOCK(1, 1, )
  MFMA_BLOCK(1, 0, VM0)
  RDA(1, 0) RDB(1, 0)
  MFMA_BLOCK(0, 0, )
  RDB(1, 1)
  MFMA_BLOCK(0, 1, )
  RDA(1, 1)
  MFMA_BLOCK(1, 1, )
  DOMFMA(1, 0)

  // ---- C write ----
#pragma unroll
  for (int mf = 0; mf < 8; ++mf)
#pragma unroll
    for (int nf = 0; nf < 4; ++nf)
#pragma unroll
      for (int j = 0; j < 4; ++j) {
        float v = acc[mf][nf][j];
        size_t idx = (size_t)(bm + mf * 32 + wm * 16 + kq * 4 + j) * C_DIM +
                     (bn + nf * 64 + wn * 16 + fr);
        if (mode == 0) {
          outK[idx] = __expf(fminf(v, 60.f));
        } else if (mode == 1) {
          outV[idx] = f2bf(v);
        } else {
          outR[idx] = f2bf(1.f / (1.f + __expf(-v)));
        }
      }
}

// ---------------- output GEMM (2-phase 128x64, proven R2 form) -------------
__global__ __launch_bounds__(256) void gemm_out(const ushort_t* __restrict__ A,
                                                const ushort_t* __restrict__ Bw,
                                                float* __restrict__ outF) {
  constexpr int K = 1024;
  constexpr int NT = K / 32;
  constexpr int BN = 64;
  constexpr int NF = BN / 32;
  __shared__ ushort_t As[2][128 * 32];
  __shared__ ushort_t Bs[2][BN * 32];

  const int tid = threadIdx.x;
  const int lane = tid & 63;
  const int wave = tid >> 6;
  const int bm = blockIdx.x * 128;
  const int bn = blockIdx.y * BN;

  const int wr = (wave >> 1) * 64;
  const int wc = (wave & 1) * (BN / 2);

  f32x4 acc[4][NF];
#pragma unroll
  for (int m = 0; m < 4; ++m)
#pragma unroll
    for (int n = 0; n < NF; ++n) acc[m][n] = (f32x4){0.f, 0.f, 0.f, 0.f};

  const int srow = tid >> 2;
  const int scol = (((tid & 3) ^ ((srow >> 1) & 3)) * 8);
  const ushort_t* Ag = A + (size_t)(bm + srow) * K + scol;
  const ushort_t* Bg = Bw + (size_t)(bn + srow) * K + scol;
  ushort_t* AsP0 = &As[0][tid * 8];
  ushort_t* BsP0 = &Bs[0][tid * 8];
  ushort_t* AsP1 = &As[1][tid * 8];
  ushort_t* BsP1 = &Bs[1][tid * 8];

  const int fr = lane & 15;
  const int kq = lane >> 4;
  const int ps = (kq ^ ((fr >> 1) & 3)) * 8;

  auto stage = [&](int buf, int k0) {
    ushort_t* ap = buf ? AsP1 : AsP0;
    ushort_t* bp = buf ? BsP1 : BsP0;
    gload_lds16(Ag + k0, ap);
    gload_lds16(Ag + (size_t)64 * K + k0, ap + 64 * 32);
    gload_lds16(Bg + k0, bp);
  };

  stage(0, 0);
  asm volatile("s_waitcnt vmcnt(0)" ::: "memory");
  __syncthreads();

  int cur = 0;
  for (int t = 0; t < NT; ++t) {
    if (t < NT - 1) stage(cur ^ 1, (t + 1) * 32);
    short8 af[4], bfr[NF];
#pragma unroll
    for (int m = 0; m < 4; ++m)
      af[m] = *(const short8*)&As[cur][(wr + m * 16 + fr) * 32 + ps];
#pragma unroll
    for (int n = 0; n < NF; ++n)
      bfr[n] = *(const short8*)&Bs[cur][(wc + n * 16 + fr) * 32 + ps];
#pragma unroll
    for (int m = 0; m < 4; ++m)
#pragma unroll
      for (int n = 0; n < NF; ++n)
        acc[m][n] = __builtin_amdgcn_mfma_f32_16x16x32_bf16(af[m], bfr[n], acc[m][n], 0, 0, 0);
    asm volatile("s_waitcnt vmcnt(0)" ::: "memory");
    __syncthreads();
    cur ^= 1;
  }

  const int crow0 = (lane >> 4) * 4;
#pragma unroll
  for (int m = 0; m < 4; ++m)
#pragma unroll
    for (int n = 0; n < NF; ++n)
#pragma unroll
      for (int j = 0; j < 4; ++j)
        outF[(size_t)(bm + wr + m * 16 + crow0 + j) * C_DIM + (bn + wc + n * 16 + fr)] =
            acc[m][n][j];
}

// ---------------- wkv chunked scan -----------------------------------------
__global__ void wkv_phaseA(const float* __restrict__ kk, const ushort_t* __restrict__ vv,
                           const float* __restrict__ td,
                           float* __restrict__ sa, float* __restrict__ sb,
                           float* __restrict__ sp) {
  int gid = blockIdx.x * 256 + threadIdx.x;
  int c = gid & (C_DIM - 1);
  int ch = (gid >> 10) & (NCH - 1);
  int b = gid >> 15;
  float w = td[c] * (1.f / T_LEN);
  size_t base = ((size_t)b * T_LEN + ch * CHL) * C_DIM + c;
  float a = 0.f, bb = 0.f, p = -1e38f;
  for (int t = 0; t < CHL; ++t) {
    float kt = kk[base + (size_t)t * C_DIM];
    float vt = bf2f(vv[base + (size_t)t * C_DIM]);
    float no2 = fmaxf(w + p, kt);
    float e1 = __expf(w + p - no2);
    float e2 = __expf(kt - no2);
    a = e1 * a + e2 * vt;
    bb = e1 * bb + e2;
    p = no2;
  }
  sa[gid] = a; sb[gid] = bb; sp[gid] = p;
}

__global__ void wkv_phaseB(const float* __restrict__ td,
                           float* __restrict__ sa, float* __restrict__ sb,
                           float* __restrict__ sp) {
  int gid = blockIdx.x * 256 + threadIdx.x;
  int c = gid & (C_DIM - 1);
  int b = gid >> 10;
  float wL = td[c] * (1.f / T_LEN) * (float)CHL;
  float a = 0.f, bb = 0.f, p = -1e38f;
  for (int ch = 0; ch < NCH; ++ch) {
    size_t idx = ((size_t)b * NCH + ch) * C_DIM + c;
    float ac = sa[idx], bc = sb[idx], pc = sp[idx];
    sa[idx] = a; sb[idx] = bb; sp[idx] = p;
    float pn = fmaxf(p + wL, pc);
    float e1 = __expf(p + wL - pn);
    float e2 = __expf(pc - pn);
    a = e1 * a + e2 * ac;
    bb = e1 * bb + e2 * bc;
    p = pn;
  }
}

__global__ void wkv_phaseC(const float* __restrict__ kk, const ushort_t* __restrict__ vv,
                           const ushort_t* __restrict__ sr, const float* __restrict__ td,
                           const float* __restrict__ tf,
                           const float* __restrict__ sa, const float* __restrict__ sb,
                           const float* __restrict__ sp, ushort_t* __restrict__ sy) {
  int gid = blockIdx.x * 256 + threadIdx.x;
  int c = gid & (C_DIM - 1);
  int ch = (gid >> 10) & (NCH - 1);
  int b = gid >> 15;
  float w = td[c] * (1.f / T_LEN);
  float u = tf[c] * (1.f / T_LEN);
  size_t base = ((size_t)b * T_LEN + ch * CHL) * C_DIM + c;
  float a = sa[gid], bb = sb[gid], p = sp[gid];
  for (int t = 0; t < CHL; ++t) {
    float kt = kk[base + (size_t)t * C_DIM];
    float vt = bf2f(vv[base + (size_t)t * C_DIM]);
    float no = fmaxf(p, u + kt);
    float e1 = __expf(p - no);
    float e2 = __expf(u + kt - no);
    float y = (e1 * a + e2 * vt) / (e1 * bb + e2);
    float srv = bf2f(sr[base + (size_t)t * C_DIM]);
    sy[base + (size_t)t * C_DIM] = f2bf(srv * y);
    float no2 = fmaxf(w + p, kt);
    e1 = __expf(w + p - no2);
    e2 = __expf(kt - no2);
    a = e1 * a + e2 * vt;
    bb = e1 * bb + e2;
    p = no2;
  }
}

// ---------------------------------------------------------------------------
extern "C" void kernel_launch(void* const* d_in, const int* in_sizes, int n_in,
                              void* d_out, int out_size, void* d_ws, size_t ws_size,
                              hipStream_t stream) {
  const float* x  = (const float*)d_in[0];
  const float* td = (const float*)d_in[1];
  const float* tf = (const float*)d_in[2];
  const float* tm = (const float*)d_in[3];
  const float* cm = (const float*)d_in[4];
  const float* Wk = (const float*)d_in[5];
  const float* Wv = (const float*)d_in[6];
  const float* Wr = (const float*)d_in[7];
  const float* Wo = (const float*)d_in[8];

  const size_t MC = (size_t)M_ROWS * C_DIM;
  const size_t CC = (size_t)C_DIM * C_DIM;

  char* ws = (char*)d_ws;
  ushort_t* xmb = (ushort_t*)ws; ws += MC * 2;
  ushort_t* Wb  = (ushort_t*)ws; ws += 4 * CC * 2;
  float*    kk  = (float*)ws;    ws += MC * 4;
  ushort_t* vv  = (ushort_t*)ws; ws += MC * 2;
  ushort_t* sr  = (ushort_t*)ws; ws += MC * 2;
  ushort_t* sy  = (ushort_t*)ws; ws += MC * 2;
  float* sa = (float*)ws; ws += (size_t)B_SZ * NCH * C_DIM * 4;
  float* sb = (float*)ws; ws += (size_t)B_SZ * NCH * C_DIM * 4;
  float* sp = (float*)ws; ws += (size_t)B_SZ * NCH * C_DIM * 4;

  cvt_w_kernel<<<(4 * CC / 4) / 256, 256, 0, stream>>>(Wk, Wv, Wr, Wo, Wb);
  xm_kernel<<<(MC / 4) / 256, 256, 0, stream>>>(x, tm, cm, xmb);

  // fused k/v/r projections: 8-phase 256^2 template, 384 blocks
  gemm256<<<dim3(384), 512, 0, stream>>>(xmb, Wb, kk, vv, sr);

  wkv_phaseA<<<(B_SZ * NCH * C_DIM) / 256, 256, 0, stream>>>(kk, vv, td, sa, sb, sp);
  wkv_phaseB<<<(B_SZ * C_DIM) / 256, 256, 0, stream>>>(td, sa, sb, sp);
  wkv_phaseC<<<(B_SZ * NCH * C_DIM) / 256, 256, 0, stream>>>(kk, vv, sr, td, tf, sa, sb, sp, sy);

  // output projection
  gemm_out<<<dim3(M_ROWS / 128, C_DIM / 64), 256, 0, stream>>>(sy, Wb + 3 * CC, (float*)d_out);
}

// Round 4
// 165.977 us; speedup vs baseline: 1.0312x; 1.0312x over previous
//
#include <hip/hip_runtime.h>
#include <hip/hip_bf16.h>
#include <stdint.h>

// Problem constants (match reference)
#define B_SZ 8
#define T_LEN 1024
#define C_DIM 1024
#define M_ROWS (B_SZ * T_LEN)   // 8192
#define NCH 32
#define CHL (T_LEN / NCH)       // 32

typedef unsigned short ushort_t;
typedef __attribute__((ext_vector_type(8))) short short8;
typedef __attribute__((ext_vector_type(4))) float f32x4;
typedef __attribute__((ext_vector_type(4))) unsigned short us4;

static __device__ __forceinline__ float bf2f(ushort_t u) {
  union { unsigned int i; float f; } x; x.i = ((unsigned int)u) << 16; return x.f;
}
static __device__ __forceinline__ ushort_t f2bf(float f) {
  union { float f; unsigned int i; } x; x.f = f;
  unsigned int r = x.i + 0x7fffu + ((x.i >> 16) & 1u);
  return (ushort_t)(r >> 16);
}

static __device__ __forceinline__ void gload_lds16(const void* g, void* l) {
  __builtin_amdgcn_global_load_lds(
      (const __attribute__((address_space(1))) void*)g,
      (__attribute__((address_space(3))) void*)l, 16, 0, 0);
}

// ---------------- weight f32 -> bf16 conversion (vectorized x4) ------------
__global__ void cvt_w_kernel(const float* __restrict__ wk, const float* __restrict__ wv,
                             const float* __restrict__ wr, const float* __restrict__ wo,
                             ushort_t* __restrict__ out) {
  int gid = blockIdx.x * 256 + threadIdx.x;
  int which = gid >> 18;
  int off = (gid << 2) & ((1 << 20) - 1);
  const float* src = which == 0 ? wk : which == 1 ? wv : which == 2 ? wr : wo;
  float4 v = *(const float4*)(src + off);
  us4 o = {f2bf(v.x), f2bf(v.y), f2bf(v.z), f2bf(v.w)};
  *(us4*)(out + (size_t)gid * 4) = o;
}

// ---------------- time-shift mixing -> bf16 xm (vectorized x4) -------------
__global__ void xm_kernel(const float* __restrict__ x, const float* __restrict__ tm,
                          const float* __restrict__ cm, ushort_t* __restrict__ xmb) {
  int gid = blockIdx.x * 256 + threadIdx.x;
  int c4 = (gid & (C_DIM / 4 - 1)) * 4;
  int t = (gid >> 8) & (T_LEN - 1);
  const float4 zero = {0.f, 0.f, 0.f, 0.f};
  float4 xv = *(const float4*)(x + (size_t)gid * 4);
  float4 xp = (t > 0) ? *(const float4*)(x + (size_t)gid * 4 - C_DIM) : zero;
  float4 xn = (t < T_LEN - 1) ? *(const float4*)(x + (size_t)gid * 4 + C_DIM) : zero;
  float4 tmv = *(const float4*)(tm + c4);
  float4 cmv = *(const float4*)(cm + c4);
  float4 xc = (c4 < C_DIM / 2) ? xp : xn;
  us4 o;
  o.x = f2bf(xv.x * tmv.x + xp.x * (1.f - tmv.x) + xc.x * cmv.x);
  o.y = f2bf(xv.y * tmv.y + xp.y * (1.f - tmv.y) + xc.y * cmv.y);
  o.z = f2bf(xv.z * tmv.z + xp.z * (1.f - tmv.z) + xc.z * cmv.z);
  o.w = f2bf(xv.w * tmv.w + xp.w * (1.f - tmv.w) + xc.w * cmv.w);
  *(us4*)(xmb + (size_t)gid * 4) = o;
}

// ---------------- bf16 NT GEMM, 128x128, dbuf + prefetch-overlap -----------
// FUSED=1: A=xmb, Bw=[Wk|Wv|Wr]; grid 1536 1-D; jb 0..23: mode=jb>>3
//          (0:kk f32 exp-clamp, 1:vv bf16, 2:sr bf16 sigmoid), bn=(jb&7)*128.
// FUSED=0: A=sy, Bw=Wo; grid 512 1-D; jb 0..7, mode 3 -> f32 d_out.
// XCD swizzle: xcd = bid&7 owns bm-tiles [xcd*8, xcd*8+8) across all jb
// (8 x 256KB A-slice = 2MB, L2-fit).
// LDS slot swizzle: physical 8-elt slot = logical ^ ((row>>1)&3); applied on
// pre-swizzled global SOURCE column (linear gload_lds dest) + swizzled read.
template <int FUSED>
__global__ __launch_bounds__(256) void gemm_bt(const ushort_t* __restrict__ A,
                                               const ushort_t* __restrict__ Bw,
                                               float* __restrict__ outF,
                                               ushort_t* __restrict__ outV,
                                               ushort_t* __restrict__ outR) {
  constexpr int K = 1024;
  constexpr int NT = K / 32;           // 32 K-steps
  __shared__ ushort_t As[2][128 * 32];
  __shared__ ushort_t Bs[2][128 * 32];

  const int tid = threadIdx.x;
  const int lane = tid & 63;
  const int wave = tid >> 6;

  const int bid = blockIdx.x;
  const int xcd = bid & 7;
  const int r = bid >> 3;
  const int bm = (xcd * 8 + (r & 7)) * 128;
  const int jb = r >> 3;                     // fused: 0..23, out: 0..7
  const int mode = FUSED ? (jb >> 3) : 3;
  const int bn = FUSED ? (jb & 7) * 128 : jb * 128;
  const ushort_t* Bp = FUSED ? (Bw + ((size_t)(jb >> 3) << 20)) : Bw;

  const int wr = (wave >> 1) * 64;         // wave row offset
  const int wc = (wave & 1) * 64;          // wave col offset

  f32x4 acc[4][4];
#pragma unroll
  for (int m = 0; m < 4; ++m)
#pragma unroll
    for (int n = 0; n < 4; ++n) acc[m][n] = (f32x4){0.f, 0.f, 0.f, 0.f};

  // staging addressing (pre-swizzled global source column)
  const int srow = tid >> 2;                         // 0..63
  const int scol = (((tid & 3) ^ ((srow >> 1) & 3)) * 8);
  const ushort_t* Ag = A + (size_t)(bm + srow) * K + scol;
  const ushort_t* Bg = Bp + (size_t)(bn + srow) * K + scol;
  ushort_t* AsP0 = &As[0][tid * 8];
  ushort_t* BsP0 = &Bs[0][tid * 8];
  ushort_t* AsP1 = &As[1][tid * 8];
  ushort_t* BsP1 = &Bs[1][tid * 8];

  // read addressing: physical slot = kq ^ ((row>>1)&3) == kq ^ ((fr>>1)&3)
  const int fr = lane & 15;
  const int kq = lane >> 4;
  const int ps = (kq ^ ((fr >> 1) & 3)) * 8;

  auto stage = [&](int buf, int k0) {
    ushort_t* ap = buf ? AsP1 : AsP0;
    ushort_t* bp = buf ? BsP1 : BsP0;
    gload_lds16(Ag + k0, ap);
    gload_lds16(Ag + (size_t)64 * K + k0, ap + 64 * 32);
    gload_lds16(Bg + k0, bp);
    gload_lds16(Bg + (size_t)64 * K + k0, bp + 64 * 32);
  };

  stage(0, 0);
  asm volatile("s_waitcnt vmcnt(0)" ::: "memory");
  __syncthreads();

  int cur = 0;
  for (int t = 0; t < NT; ++t) {
    if (t < NT - 1) stage(cur ^ 1, (t + 1) * 32);
    short8 af[4], bfr[4];
#pragma unroll
    for (int m = 0; m < 4; ++m)
      af[m] = *(const short8*)&As[cur][(wr + m * 16 + fr) * 32 + ps];
#pragma unroll
    for (int n = 0; n < 4; ++n)
      bfr[n] = *(const short8*)&Bs[cur][(wc + n * 16 + fr) * 32 + ps];
#pragma unroll
    for (int m = 0; m < 4; ++m)
#pragma unroll
      for (int n = 0; n < 4; ++n)
        acc[m][n] = __builtin_amdgcn_mfma_f32_16x16x32_bf16(af[m], bfr[n], acc[m][n], 0, 0, 0);
    asm volatile("s_waitcnt vmcnt(0)" ::: "memory");
    __syncthreads();
    cur ^= 1;
  }

  const int crow0 = (lane >> 4) * 4;   // C/D: col=lane&15, row=(lane>>4)*4+j
#pragma unroll
  for (int m = 0; m < 4; ++m)
#pragma unroll
    for (int n = 0; n < 4; ++n)
#pragma unroll
      for (int j = 0; j < 4; ++j) {
        float v = acc[m][n][j];
        size_t idx = (size_t)(bm + wr + m * 16 + crow0 + j) * C_DIM + (bn + wc + n * 16 + fr);
        if (mode == 0) {
          outF[idx] = __expf(fminf(v, 60.f));
        } else if (mode == 1) {
          outV[idx] = f2bf(v);
        } else if (mode == 2) {
          outR[idx] = f2bf(1.f / (1.f + __expf(-v)));
        } else {
          outF[idx] = v;
        }
      }
}

// ---------------- wkv chunked scan -----------------------------------------
// Phase A: per (b, chunk, c) compute chunk-local (a, b, p) from zero init.
__global__ void wkv_phaseA(const float* __restrict__ kk, const ushort_t* __restrict__ vv,
                           const float* __restrict__ td,
                           float* __restrict__ sa, float* __restrict__ sb,
                           float* __restrict__ sp) {
  int gid = blockIdx.x * 256 + threadIdx.x;
  int c = gid & (C_DIM - 1);
  int ch = (gid >> 10) & (NCH - 1);
  int b = gid >> 15;
  float w = td[c] * (1.f / T_LEN);
  size_t base = ((size_t)b * T_LEN + ch * CHL) * C_DIM + c;
  float a = 0.f, bb = 0.f, p = -1e38f;
  for (int t = 0; t < CHL; ++t) {
    float kt = kk[base + (size_t)t * C_DIM];
    float vt = bf2f(vv[base + (size_t)t * C_DIM]);
    float no2 = fmaxf(w + p, kt);
    float e1 = __expf(w + p - no2);
    float e2 = __expf(kt - no2);
    a = e1 * a + e2 * vt;
    bb = e1 * bb + e2;
    p = no2;
  }
  sa[gid] = a; sb[gid] = bb; sp[gid] = p;
}

// Phase C2: per (b, chunk, c): inline prefix-combine of chunks < ch (uniform
// per block; state arrays are 4 MB -> L2-resident), then rerun scan emitting
// sy = bf16( sigmoid(r) * y ).
__global__ void wkv_phaseC2(const float* __restrict__ kk, const ushort_t* __restrict__ vv,
                            const ushort_t* __restrict__ sr, const float* __restrict__ td,
                            const float* __restrict__ tf,
                            const float* __restrict__ sa, const float* __restrict__ sb,
                            const float* __restrict__ sp, ushort_t* __restrict__ sy) {
  int gid = blockIdx.x * 256 + threadIdx.x;
  int c = gid & (C_DIM - 1);
  int ch = (gid >> 10) & (NCH - 1);
  int b = gid >> 15;
  float w = td[c] * (1.f / T_LEN);
  float u = tf[c] * (1.f / T_LEN);
  float wL = w * (float)CHL;

  // incoming state for this chunk = sequential combine of chunks 0..ch-1
  float a = 0.f, bb = 0.f, p = -1e38f;
  size_t sbase = ((size_t)b * NCH) * C_DIM + c;
  for (int j = 0; j < ch; ++j) {
    float ac = sa[sbase + (size_t)j * C_DIM];
    float bc = sb[sbase + (size_t)j * C_DIM];
    float pc = sp[sbase + (size_t)j * C_DIM];
    float pn = fmaxf(p + wL, pc);
    float e1 = __expf(p + wL - pn);
    float e2 = __expf(pc - pn);
    a = e1 * a + e2 * ac;
    bb = e1 * bb + e2 * bc;
    p = pn;
  }

  size_t base = ((size_t)b * T_LEN + ch * CHL) * C_DIM + c;
  for (int t = 0; t < CHL; ++t) {
    float kt = kk[base + (size_t)t * C_DIM];
    float vt = bf2f(vv[base + (size_t)t * C_DIM]);
    float no = fmaxf(p, u + kt);
    float e1 = __expf(p - no);
    float e2 = __expf(u + kt - no);
    float y = (e1 * a + e2 * vt) / (e1 * bb + e2);
    float srv = bf2f(sr[base + (size_t)t * C_DIM]);
    sy[base + (size_t)t * C_DIM] = f2bf(srv * y);
    float no2 = fmaxf(w + p, kt);
    e1 = __expf(w + p - no2);
    e2 = __expf(kt - no2);
    a = e1 * a + e2 * vt;
    bb = e1 * bb + e2;
    p = no2;
  }
}

// ---------------------------------------------------------------------------
extern "C" void kernel_launch(void* const* d_in, const int* in_sizes, int n_in,
                              void* d_out, int out_size, void* d_ws, size_t ws_size,
                              hipStream_t stream) {
  const float* x  = (const float*)d_in[0];
  const float* td = (const float*)d_in[1];
  const float* tf = (const float*)d_in[2];
  const float* tm = (const float*)d_in[3];
  const float* cm = (const float*)d_in[4];
  const float* Wk = (const float*)d_in[5];
  const float* Wv = (const float*)d_in[6];
  const float* Wr = (const float*)d_in[7];
  const float* Wo = (const float*)d_in[8];

  const size_t MC = (size_t)M_ROWS * C_DIM;
  const size_t CC = (size_t)C_DIM * C_DIM;

  char* ws = (char*)d_ws;
  ushort_t* xmb = (ushort_t*)ws; ws += MC * 2;
  ushort_t* Wb  = (ushort_t*)ws; ws += 4 * CC * 2;
  float*    kk  = (float*)ws;    ws += MC * 4;
  ushort_t* vv  = (ushort_t*)ws; ws += MC * 2;
  ushort_t* sr  = (ushort_t*)ws; ws += MC * 2;
  ushort_t* sy  = (ushort_t*)ws; ws += MC * 2;
  float* sa = (float*)ws; ws += (size_t)B_SZ * NCH * C_DIM * 4;
  float* sb = (float*)ws; ws += (size_t)B_SZ * NCH * C_DIM * 4;
  float* sp = (float*)ws; ws += (size_t)B_SZ * NCH * C_DIM * 4;

  cvt_w_kernel<<<(4 * CC / 4) / 256, 256, 0, stream>>>(Wk, Wv, Wr, Wo, Wb);
  xm_kernel<<<(MC / 4) / 256, 256, 0, stream>>>(x, tm, cm, xmb);

  // fused k/v/r projections: 1536 blocks, XCD-swizzled
  gemm_bt<1><<<dim3(1536), 256, 0, stream>>>(xmb, Wb, kk, vv, sr);

  wkv_phaseA<<<(B_SZ * NCH * C_DIM) / 256, 256, 0, stream>>>(kk, vv, td, sa, sb, sp);
  wkv_phaseC2<<<(B_SZ * NCH * C_DIM) / 256, 256, 0, stream>>>(kk, vv, sr, td, tf, sa, sb, sp, sy);

  // output projection: 512 blocks, XCD-swizzled
  gemm_bt<0><<<dim3(512), 256, 0, stream>>>(sy, Wb + 3 * CC, (float*)d_out, nullptr, nullptr);
}